// Round 2
// baseline (277.565 us; speedup 1.0000x reference)
//
#include <hip/hip_runtime.h>
#include <hip/hip_fp16.h>

#define BB 2
#define AA 512
#define NN 1024
#define FF 64
#define DIN 128
#define DOUT 128
#define TH 25
#define NSPLIT 4
#define NIT 4   // NN / (16 triples * 4 tiles/wave-iter * NSPLIT) per wave

typedef _Float16 half8 __attribute__((ext_vector_type(8)));
typedef _Float16 half4v __attribute__((ext_vector_type(4)));
typedef float floatx4 __attribute__((ext_vector_type(4)));

__device__ __forceinline__ float ssp_f(float x) {
    return __logf(0.5f * __expf(x) + 0.5f);  // softplus(x) - ln2
}

__device__ __forceinline__ float cutcos(float r) {
    float c = 0.5f * (__cosf(r * (3.14159265358979323846f / 5.0f)) + 1.0f);
    return (r < 5.0f) ? c : 0.0f;
}

// packed-f16 shifted softplus on a half2 (v_exp_f16/v_log_f16 + pk ops)
__device__ __forceinline__ __half2 ssp2(__half2 x) {
    const __half2 hlf = __float2half2_rn(0.5f);
    return h2log(__hfma2(h2exp(x), hlf, hlf));
}

// pack two f32 -> __half2 (v_cvt_pkrtz_f16_f32); bit-cast through memory
__device__ __forceinline__ __half2 pk2(float a, float b) {
    auto v = __builtin_amdgcn_cvt_pkrtz(a, b);  // __fp16 ext_vector(2)
    __half2 r;
    __builtin_memcpy(&r, &v, sizeof(r));
    return r;
}

// pack four half2 -> half8 (register concat for MFMA operand)
__device__ __forceinline__ half8 pack8(__half2 a, __half2 b, __half2 c, __half2 d) {
    half8 r;
    __builtin_memcpy(reinterpret_cast<char*>(&r) + 0,  &a, 4);
    __builtin_memcpy(reinterpret_cast<char*>(&r) + 4,  &b, 4);
    __builtin_memcpy(reinterpret_cast<char*>(&r) + 8,  &c, 4);
    __builtin_memcpy(reinterpret_cast<char*>(&r) + 12, &d, 4);
    return r;
}

// ---- d_ws layout (bytes) ----
#define OFF_Y       0                                              // 128 KB
#define OFF_PARTIAL (OFF_Y + (size_t)BB * AA * FF * 2)             // 1 MB
#define OFF_B1      (OFF_PARTIAL + (size_t)NSPLIT * BB * AA * FF * 4)
#define OFF_B2      (OFF_B1 + 4 * 64 * 8 * 2)                      // B1tab 4 KB
#define OFF_B1P     (OFF_B2 + 8 * 64 * 8 * 2)                      // B2tab 8 KB
#define OFF_B2F     (OFF_B1P + 4 * 2 * 64 * 2 * 2)                 // b1 pairs 2 KB
                                                                   // B2F 4 KB

// Kernel 1: in2f (all blocks) + weight-fragment prep (block 0 only).
// mm1 feature PERMUTATION: block g, D-row m -> feature base_g + 8*(m>>2) + (m&3),
// base = {0,4,32,36}. This makes mm1's per-lane D registers exactly mm2's
// B-operand fragment in natural f1 order (a2 built by register packing, no LDS).
__global__ void in2f_prep_kernel(const float* __restrict__ x,
                                 const float* __restrict__ Wi,
                                 _Float16* __restrict__ y,
                                 const float* __restrict__ W_t1, const float* __restrict__ b_t1,
                                 const float* __restrict__ W_t2, const float* __restrict__ b_t2,
                                 _Float16* __restrict__ B1tab, _Float16* __restrict__ B2tab,
                                 _Float16* __restrict__ B1Ptab, float* __restrict__ B2Ftab) {
    __shared__ float xs[DIN];
    const int ba = blockIdx.x;
    const int t = threadIdx.x;  // 64
    xs[t] = x[ba * DIN + t];
    xs[t + 64] = x[ba * DIN + 64 + t];
    __syncthreads();
    float acc = 0.f;
#pragma unroll 8
    for (int d = 0; d < DIN; ++d) acc += xs[d] * Wi[d * FF + t];
    y[ba * FF + t] = (_Float16)acc;

    if (ba == 0) {
        const int lane = t, quad = t >> 4, l16 = t & 15;
        const int baseg[4] = {0, 4, 32, 36};
#pragma unroll
        for (int g = 0; g < 4; ++g) {
            // B1: A-operand row m=l16 of block g holds permuted feature
            const int feat_m = baseg[g] + 8 * (l16 >> 2) + (l16 & 3);
#pragma unroll
            for (int j = 0; j < 8; ++j) {
                int k = quad * 8 + j;
                B1tab[(g * 64 + lane) * 8 + j] =
                    (k < TH) ? (_Float16)W_t1[k * FF + feat_m] : (_Float16)0.f;
            }
            // b1 pairs for D rows m=4*quad+reg: feature = base_g + 8*quad + reg
#pragma unroll
            for (int e = 0; e < 2; ++e) {
                B1Ptab[((g * 2 + e) * 64 + lane) * 2 + 0] =
                    (_Float16)b_t1[baseg[g] + 8 * quad + 2 * e];
                B1Ptab[((g * 2 + e) * 64 + lane) * 2 + 1] =
                    (_Float16)b_t1[baseg[g] + 8 * quad + 2 * e + 1];
            }
            // B2 unchanged: k-dim (f1) in natural order matches permuted-mm1 output
#pragma unroll
            for (int q = 0; q < 2; ++q)
#pragma unroll
                for (int j = 0; j < 8; ++j)
                    B2tab[((g * 2 + q) * 64 + lane) * 8 + j] =
                        (_Float16)W_t2[(q * 32 + quad * 8 + j) * FF + g * 16 + l16];
            // b2 per-lane f32: f2 = g*16 + 4*quad + reg
#pragma unroll
            for (int r = 0; r < 4; ++r)
                B2Ftab[lane * 16 + g * 4 + r] = b_t2[g * 16 + 4 * quad + r];
        }
    }
}

// Kernel 2: zero-LDS main loop. Per iteration (fully unrolled, NIT=4):
//   d loads (direct global, prefetched) -> afrag regs -> mm1 -> ssp -> a2 (reg
//   pack via feature permutation) -> mm2 -> epilogue in mm2's native D layout
//   (lane (quad,l16) owns triple l16, features g*16+quad*4+r; y gathered b64).
// NOTE: bare __launch_bounds__(256) — a (256,4) bound caps VGPRs at 64 and
// causes massive scratch spilling (measured: WRITE_SIZE 401 MB vs 1.5 MB legit).
__global__ __launch_bounds__(256) void triple_kernel(
    const int* __restrict__ nbrj, const int* __restrict__ nbrk,
    const float* __restrict__ r_ij, const float* __restrict__ r_ik,
    const float* __restrict__ tmask, const float* __restrict__ d_ijk,
    const _Float16* __restrict__ B1tab, const _Float16* __restrict__ B2tab,
    const _Float16* __restrict__ B1Ptab, const float* __restrict__ B2Ftab,
    const _Float16* __restrict__ y_tab, float* __restrict__ partial) {

    __shared__ __align__(16) float red[4][FF];

    const int blk = blockIdx.x;
    const int ba = blk >> 2;
    const int split = blk & 3;
    const int b = ba >> 9;  // A = 512
    const int tid = threadIdx.x;
    const int w = tid >> 6;
    const int lane = tid & 63;
    const int quad = lane >> 4;
    const int l16 = lane & 15;

    const long ban = (long)ba * NN;
    const float* dbase = d_ijk + (long)ba * NN * TH;
    const _Float16* yb = y_tab + (long)b * (AA * FF);

    // ---- weight fragments ----
    half8 B1[4];
    half8 B2[4][2];
    __half2 b1p[4][2];
    floatx4 b2f[4];
#pragma unroll
    for (int g = 0; g < 4; ++g) {
        B1[g] = *(const half8*)(B1tab + (g * 64 + lane) * 8);
        B2[g][0] = *(const half8*)(B2tab + ((g * 2 + 0) * 64 + lane) * 8);
        B2[g][1] = *(const half8*)(B2tab + ((g * 2 + 1) * 64 + lane) * 8);
        b1p[g][0] = *(const __half2*)(B1Ptab + ((g * 2 + 0) * 64 + lane) * 2);
        b1p[g][1] = *(const __half2*)(B1Ptab + ((g * 2 + 1) * 64 + lane) * 2);
        b2f[g] = *(const floatx4*)(B2Ftab + lane * 16 + g * 4);
    }

    // ---- per-lane triple precompute: lane owns triple l16 of tile
    //      (split*16 + quad*4 + w)  (i.e. the tile this wave runs at it==quad).
    //      Iteration it fetches via 4 cheap shfl from lane it*16+l16.
    const int myn = (split * 16 + quad * 4 + w) * 16 + l16;
    const long myna = ban + myn;
    const float rijL = r_ij[myna], rikL = r_ik[myna];
    const float ivL = cutcos(rijL) * cutcos(rikL) * tmask[myna] / (rijL + rikL);
    const float wjL = rijL * ivL, wkL = rikL * ivL;
    const int pjL = nbrj[myna], pkL = nbrk[myna];

    // d pointer: row T(it)*16 + l16, cols quad*8+j; advance 1600 floats/iter
    const float* dp0 = dbase + (long)((split * 16 + w) * 16 + l16) * TH + quad * 8;
    const bool qok = (quad < 3);  // quad==3: only k=24 (j=0) is a real column

    float acc[16];
#pragma unroll
    for (int i = 0; i < 16; ++i) acc[i] = 0.f;
    const floatx4 zero4 = {0.f, 0.f, 0.f, 0.f};

    float dv[2][8];
    half4v gj[2][4], gk[2][4];
    float wjc[2], wkc[2];

    // ---- prologue: prefetch it=0 ----
    {
        const int sl = l16;
        const int pj = __shfl(pjL, sl), pk = __shfl(pkL, sl);
        wjc[0] = __shfl(wjL, sl);
        wkc[0] = __shfl(wkL, sl);
        const _Float16* pjb = yb + pj * FF + quad * 4;
        const _Float16* pkb = yb + pk * FF + quad * 4;
#pragma unroll
        for (int g = 0; g < 4; ++g) {
            gj[0][g] = *(const half4v*)(pjb + g * 16);
            gk[0][g] = *(const half4v*)(pkb + g * 16);
        }
        dv[0][0] = dp0[0];
#pragma unroll
        for (int j = 1; j < 8; ++j) dv[0][j] = qok ? dp0[j] : 0.f;
    }

#pragma unroll
    for (int it = 0; it < NIT; ++it) {
        const int cur = it & 1, nxt = cur ^ 1;

        // prefetch it+1 (overlaps MFMA/ssp chain below)
        if (it + 1 < NIT) {
            const int sl = (it + 1) * 16 + l16;
            const int pj = __shfl(pjL, sl), pk = __shfl(pkL, sl);
            wjc[nxt] = __shfl(wjL, sl);
            wkc[nxt] = __shfl(wkL, sl);
            const _Float16* pjb = yb + pj * FF + quad * 4;
            const _Float16* pkb = yb + pk * FF + quad * 4;
#pragma unroll
            for (int g = 0; g < 4; ++g) {
                gj[nxt][g] = *(const half4v*)(pjb + g * 16);
                gk[nxt][g] = *(const half4v*)(pkb + g * 16);
            }
            const float* dp = dp0 + (it + 1) * 1600;
            dv[nxt][0] = dp[0];
#pragma unroll
            for (int j = 1; j < 8; ++j) dv[nxt][j] = qok ? dp[j] : 0.f;
        }

        // afrag from registers (f32 -> packed f16)
        const half8 af = pack8(pk2(dv[cur][0], dv[cur][1]), pk2(dv[cur][2], dv[cur][3]),
                               pk2(dv[cur][4], dv[cur][5]), pk2(dv[cur][6], dv[cur][7]));

        // mm1 + ssp; permuted features make hh exactly mm2's B-frag order
        __half2 hh[8];
#pragma unroll
        for (int g = 0; g < 4; ++g) {
            floatx4 hv = __builtin_amdgcn_mfma_f32_16x16x32_f16(B1[g], af, zero4, 0, 0, 0);
            hh[2 * g]     = ssp2(__hadd2(pk2(hv[0], hv[1]), b1p[g][0]));
            hh[2 * g + 1] = ssp2(__hadd2(pk2(hv[2], hv[3]), b1p[g][1]));
        }
        const half8 a2q0 = pack8(hh[0], hh[1], hh[2], hh[3]);
        const half8 a2q1 = pack8(hh[4], hh[5], hh[6], hh[7]);

        // mm2 + epilogue in native D layout (triple = l16, feats g*16+quad*4+r)
        const __half2 wjh = __float2half2_rn(wjc[cur]);
        const __half2 wkh = __float2half2_rn(wkc[cur]);
#pragma unroll
        for (int g = 0; g < 4; ++g) {
            floatx4 w2 = __builtin_amdgcn_mfma_f32_16x16x32_f16(B2[g][0], a2q0, zero4, 0, 0, 0);
            w2 = __builtin_amdgcn_mfma_f32_16x16x32_f16(B2[g][1], a2q1, w2, 0, 0, 0);
            const __half2* yjp = (const __half2*)&gj[cur][g];
            const __half2* ykp = (const __half2*)&gk[cur][g];
            const __half2 fv0 = __hfma2(wjh, yjp[0], __hmul2(wkh, ykp[0]));
            const __half2 fv1 = __hfma2(wjh, yjp[1], __hmul2(wkh, ykp[1]));
            acc[g * 4 + 0] += (w2[0] + b2f[g][0]) * __low2float(fv0);
            acc[g * 4 + 1] += (w2[1] + b2f[g][1]) * __high2float(fv0);
            acc[g * 4 + 2] += (w2[2] + b2f[g][2]) * __low2float(fv1);
            acc[g * 4 + 3] += (w2[3] + b2f[g][3]) * __high2float(fv1);
        }
    }

    // ---- reduce over the 16 l16-lanes within each quad group ----
#pragma unroll
    for (int m = 1; m < 16; m <<= 1)
#pragma unroll
        for (int i = 0; i < 16; ++i) acc[i] += __shfl_xor(acc[i], m, 64);

    if (l16 == 0) {
#pragma unroll
        for (int g = 0; g < 4; ++g) {
            floatx4 v = {acc[g * 4 + 0], acc[g * 4 + 1], acc[g * 4 + 2], acc[g * 4 + 3]};
            *(floatx4*)&red[w][g * 16 + quad * 4] = v;
        }
    }
    __syncthreads();

    if (tid < FF)
        partial[(split * (BB * AA) + ba) * FF + tid] =
            red[0][tid] + red[1][tid] + red[2][tid] + red[3][tid];
}

// Kernel 3: sum the NSPLIT partials, f2out matvec + ssp
__global__ void out_kernel(const float* __restrict__ partial,
                           const float* __restrict__ Wf,
                           const float* __restrict__ bf,
                           float* __restrict__ out) {
    __shared__ float yag[FF];
    const int ba = blockIdx.x;
    const int t = threadIdx.x;  // 128
    if (t < FF) {
        float s = 0.f;
#pragma unroll
        for (int sp = 0; sp < NSPLIT; ++sp)
            s += partial[(sp * (BB * AA) + ba) * FF + t];
        yag[t] = s;
    }
    __syncthreads();
    float a = bf[t];
#pragma unroll 8
    for (int f = 0; f < FF; ++f) a += yag[f] * Wf[f * DOUT + t];
    out[(long)ba * DOUT + t] = ssp_f(a);
}

extern "C" void kernel_launch(void* const* d_in, const int* in_sizes, int n_in,
                              void* d_out, int out_size, void* d_ws, size_t ws_size,
                              hipStream_t stream) {
    const float* x       = (const float*)d_in[0];
    const float* r_ij    = (const float*)d_in[2];
    const float* r_ik    = (const float*)d_in[3];
    const int*   nbrj    = (const int*)d_in[7];
    const int*   nbrk    = (const int*)d_in[8];
    const float* tmask   = (const float*)d_in[9];
    const float* d_ijk   = (const float*)d_in[10];
    const float* W_in2f  = (const float*)d_in[11];
    const float* W_t1    = (const float*)d_in[12];
    const float* b_t1    = (const float*)d_in[13];
    const float* W_t2    = (const float*)d_in[14];
    const float* b_t2    = (const float*)d_in[15];
    const float* W_f2out = (const float*)d_in[16];
    const float* b_f2out = (const float*)d_in[17];
    float* out = (float*)d_out;

    char* ws = (char*)d_ws;
    _Float16* y      = (_Float16*)(ws + OFF_Y);
    float* partial   = (float*)(ws + OFF_PARTIAL);
    _Float16* B1tab  = (_Float16*)(ws + OFF_B1);
    _Float16* B2tab  = (_Float16*)(ws + OFF_B2);
    _Float16* B1Ptab = (_Float16*)(ws + OFF_B1P);
    float* B2Ftab    = (float*)(ws + OFF_B2F);

    in2f_prep_kernel<<<BB * AA, 64, 0, stream>>>(x, W_in2f, y, W_t1, b_t1,
                                                 W_t2, b_t2, B1tab, B2tab,
                                                 B1Ptab, B2Ftab);
    triple_kernel<<<BB * AA * NSPLIT, 256, 0, stream>>>(nbrj, nbrk, r_ij, r_ik,
                                                        tmask, d_ijk, B1tab, B2tab,
                                                        B1Ptab, B2Ftab, y, partial);
    out_kernel<<<BB * AA, 128, 0, stream>>>(partial, W_f2out, b_f2out, out);
}

// Round 3
// 250.335 us; speedup vs baseline: 1.1088x; 1.1088x over previous
//
#include <hip/hip_runtime.h>
#include <hip/hip_fp16.h>

#define BB 2
#define AA 512
#define NN 1024
#define FF 64
#define DIN 128
#define DOUT 128
#define TH 25
#define ASTRIDE 40   // halves per a_tile row (16B-aligned frag base)
#define HSTRIDE 72   // halves per f_tile row (16B-aligned, 144B row pitch)
#define NSPLIT 4
#define NIT 4        // tiles per wave

typedef _Float16 half8 __attribute__((ext_vector_type(8)));
typedef _Float16 half4v __attribute__((ext_vector_type(4)));
typedef float floatx4 __attribute__((ext_vector_type(4)));

__device__ __forceinline__ float ssp_f(float x) {
    return __logf(0.5f * __expf(x) + 0.5f);  // softplus(x) - ln2
}

__device__ __forceinline__ float cutcos(float r) {
    float c = 0.5f * (__cosf(r * (3.14159265358979323846f / 5.0f)) + 1.0f);
    return (r < 5.0f) ? c : 0.0f;
}

// packed-f16 shifted softplus on a half2 (v_exp_f16/v_log_f16 + pk ops)
__device__ __forceinline__ __half2 ssp2(__half2 x) {
    const __half2 hlf = __float2half2_rn(0.5f);
    return h2log(__hfma2(h2exp(x), hlf, hlf));
}

// pack two f32 -> __half2 (v_cvt_pkrtz_f16_f32); bit-cast through memory
__device__ __forceinline__ __half2 pk2(float a, float b) {
    auto v = __builtin_amdgcn_cvt_pkrtz(a, b);  // __fp16 ext_vector(2)
    __half2 r;
    __builtin_memcpy(&r, &v, sizeof(r));
    return r;
}

// pack two half2 -> 4 x f16 for a single ds_write_b64
__device__ __forceinline__ half4v pack4(__half2 lo, __half2 hi) {
    half4v r;
    __builtin_memcpy(&r, &lo, 4);
    __builtin_memcpy(reinterpret_cast<char*>(&r) + 4, &hi, 4);
    return r;
}

// pack four half2 -> half8 (register concat for MFMA operand)
__device__ __forceinline__ half8 pack8(__half2 a, __half2 b, __half2 c, __half2 d) {
    half8 r;
    __builtin_memcpy(reinterpret_cast<char*>(&r) + 0,  &a, 4);
    __builtin_memcpy(reinterpret_cast<char*>(&r) + 4,  &b, 4);
    __builtin_memcpy(reinterpret_cast<char*>(&r) + 8,  &c, 4);
    __builtin_memcpy(reinterpret_cast<char*>(&r) + 12, &d, 4);
    return r;
}

// ---- d_ws layout (bytes) ----
#define OFF_Y       0                                              // 128 KB
#define OFF_PARTIAL (OFF_Y + (size_t)BB * AA * FF * 2)             // 1 MB
#define OFF_B1      (OFF_PARTIAL + (size_t)NSPLIT * BB * AA * FF * 4)
#define OFF_B2      (OFF_B1 + 4 * 64 * 8 * 2)                      // B1tab 4 KB
#define OFF_B1P     (OFF_B2 + 8 * 64 * 8 * 2)                      // B2tab 8 KB
#define OFF_B2F     (OFF_B1P + 4 * 2 * 64 * 2 * 2)                 // b1 pairs 2 KB
                                                                   // B2F 4 KB

// Kernel 1: in2f (all blocks) + weight-fragment prep (block 0 only).
// mm1 feature PERMUTATION: block g, D-row m -> feature base_g + 8*(m>>2) + (m&3),
// base = {0,4,32,36}. This makes mm1's per-lane D registers exactly mm2's
// B-operand fragment in natural f1 order (a2 built by register packing, no LDS).
__global__ void in2f_prep_kernel(const float* __restrict__ x,
                                 const float* __restrict__ Wi,
                                 _Float16* __restrict__ y,
                                 const float* __restrict__ W_t1, const float* __restrict__ b_t1,
                                 const float* __restrict__ W_t2, const float* __restrict__ b_t2,
                                 _Float16* __restrict__ B1tab, _Float16* __restrict__ B2tab,
                                 _Float16* __restrict__ B1Ptab, float* __restrict__ B2Ftab) {
    __shared__ float xs[DIN];
    const int ba = blockIdx.x;
    const int t = threadIdx.x;  // 64
    xs[t] = x[ba * DIN + t];
    xs[t + 64] = x[ba * DIN + 64 + t];
    __syncthreads();
    float acc = 0.f;
#pragma unroll 8
    for (int d = 0; d < DIN; ++d) acc += xs[d] * Wi[d * FF + t];
    y[ba * FF + t] = (_Float16)acc;

    if (ba == 0) {
        const int lane = t, quad = t >> 4, l16 = t & 15;
        const int baseg[4] = {0, 4, 32, 36};
#pragma unroll
        for (int g = 0; g < 4; ++g) {
            // B1: A-operand row m=l16 of block g holds permuted feature
            const int feat_m = baseg[g] + 8 * (l16 >> 2) + (l16 & 3);
#pragma unroll
            for (int j = 0; j < 8; ++j) {
                int k = quad * 8 + j;
                B1tab[(g * 64 + lane) * 8 + j] =
                    (k < TH) ? (_Float16)W_t1[k * FF + feat_m] : (_Float16)0.f;
            }
            // b1 pairs for D rows m=4*quad+reg: feature = base_g + 8*quad + reg
#pragma unroll
            for (int e = 0; e < 2; ++e) {
                B1Ptab[((g * 2 + e) * 64 + lane) * 2 + 0] =
                    (_Float16)b_t1[baseg[g] + 8 * quad + 2 * e];
                B1Ptab[((g * 2 + e) * 64 + lane) * 2 + 1] =
                    (_Float16)b_t1[baseg[g] + 8 * quad + 2 * e + 1];
            }
            // B2 unchanged: k-dim (f1) in natural order matches permuted-mm1 output
#pragma unroll
            for (int q = 0; q < 2; ++q)
#pragma unroll
                for (int j = 0; j < 8; ++j)
                    B2tab[((g * 2 + q) * 64 + lane) * 8 + j] =
                        (_Float16)W_t2[(q * 32 + quad * 8 + j) * FF + g * 16 + l16];
            // b2 per-lane f32: f2 = g*16 + 4*quad + reg
#pragma unroll
            for (int r = 0; r < 4; ++r)
                B2Ftab[lane * 16 + g * 4 + r] = b_t2[g * 16 + 4 * quad + r];
        }
    }
}

// Kernel 2: hybrid. Coalesced A staging through LDS (round-1), register-only
// mm1->mm2 chain via feature permutation (round-2), single LDS transpose trip
// for the mm2 output into the gather-epilogue layout, 16B y gathers.
// NOTE: bare __launch_bounds__(256) — a (256,4) bound caps VGPRs at 64 and
// causes massive scratch spilling (measured: WRITE_SIZE 401 MB vs 1.5 MB legit).
__global__ __launch_bounds__(256) void triple_kernel(
    const int* __restrict__ nbrj, const int* __restrict__ nbrk,
    const float* __restrict__ r_ij, const float* __restrict__ r_ik,
    const float* __restrict__ tmask, const float* __restrict__ d_ijk,
    const _Float16* __restrict__ B1tab, const _Float16* __restrict__ B2tab,
    const _Float16* __restrict__ B1Ptab, const float* __restrict__ B2Ftab,
    const _Float16* __restrict__ y_tab, float* __restrict__ partial) {

    // per-wave buffers -> no __syncthreads in main loop (same-wave DS is in-order)
    __shared__ __align__(16) _Float16 a_tile[4][16 * ASTRIDE];
    __shared__ __align__(16) _Float16 f_tile[4][16 * HSTRIDE];
    __shared__ float red[4][FF];

    const int blk = blockIdx.x;
    const int ba = blk >> 2;
    const int split = blk & 3;
    const int b = ba >> 9;  // A = 512
    const int tid = threadIdx.x;
    const int w = tid >> 6;
    const int lane = tid & 63;
    const int quad = lane >> 4;
    const int l16 = lane & 15;
    const int rA = lane >> 3;        // row group: rows rA and rA+8
    const int fc = (lane & 7) * 8;   // feature chunk base (8 f16)

    const long ban = (long)ba * NN;
    const float* dbase = d_ijk + (long)ba * NN * TH;
    const _Float16* yb = y_tab + (long)b * (AA * FF);

    // ---- weight fragments ----
    half8 B1[4];
    half8 B2[4][2];
    __half2 b1p[4][2];
    floatx4 b2f[4];
#pragma unroll
    for (int g = 0; g < 4; ++g) {
        B1[g] = *(const half8*)(B1tab + (g * 64 + lane) * 8);
        B2[g][0] = *(const half8*)(B2tab + ((g * 2 + 0) * 64 + lane) * 8);
        B2[g][1] = *(const half8*)(B2tab + ((g * 2 + 1) * 64 + lane) * 8);
        b1p[g][0] = *(const __half2*)(B1Ptab + ((g * 2 + 0) * 64 + lane) * 2);
        b1p[g][1] = *(const __half2*)(B1Ptab + ((g * 2 + 1) * 64 + lane) * 2);
        b2f[g] = *(const floatx4*)(B2Ftab + lane * 16 + g * 4);
    }

    // ---- per-lane triple precompute: lane (quad,l16) owns triple l16 of the
    //      tile this wave runs at it==quad. Iteration it fetches via shfl.
    const int myn = (split * 16 + quad * 4 + w) * 16 + l16;
    const long myna = ban + myn;
    const float rijL = r_ij[myna], rikL = r_ik[myna];
    const float ivL = cutcos(rijL) * cutcos(rikL) * tmask[myna] / (rijL + rikL);
    const float wjL = rijL * ivL, wkL = rikL * ivL;
    const int pjL = nbrj[myna], pkL = nbrk[myna];

    // zero A-tile K-pad cols 25..31 once
    for (int idx = lane; idx < 16 * 7; idx += 64) {
        int r = idx / 7, c = 25 + idx % 7;
        a_tile[w][r * ASTRIDE + c] = (_Float16)0.f;
    }

    // A staging map: 400 contiguous floats; 3 x float2/lane + 16-float tail
    int lofs2[3][2];
#pragma unroll
    for (int m = 0; m < 3; ++m)
#pragma unroll
        for (int e = 0; e < 2; ++e) {
            int s = m * 128 + lane * 2 + e;
            int r = s / TH, c = s - r * TH;
            lofs2[m][e] = r * ASTRIDE + c;
        }
    const int tofs = 15 * ASTRIDE + 9 + lane;  // tail: row 15 cols 9..24 (lane<16)

    float acc[8];
#pragma unroll
    for (int i = 0; i < 8; ++i) acc[i] = 0.f;
    const floatx4 zero4 = {0.f, 0.f, 0.f, 0.f};

    // ---- prologue: prefetch A tile for it=0 ----
    float2 pA[3];
    float pT = 0.f;
    {
        const int n0 = (split * 16 + w) * 16;
        const float* dsrc = dbase + n0 * TH;
#pragma unroll
        for (int m = 0; m < 3; ++m) pA[m] = *(const float2*)(dsrc + m * 128 + lane * 2);
        if (lane < 16) pT = dsrc[384 + lane];
    }

#pragma unroll 1
    for (int it = 0; it < NIT; ++it) {
        // 1. indices via cross-lane broadcast; issue gathers immediately
        const int sl0 = it * 16 + rA;   // lane holding triple n0+rA
        const int sl1 = sl0 + 8;        // lane holding triple n0+rA+8
        const int pj0 = __shfl(pjL, sl0), pk0 = __shfl(pkL, sl0);
        const int pj1 = __shfl(pjL, sl1), pk1 = __shfl(pkL, sl1);
        half8 gj0 = *(const half8*)(yb + pj0 * FF + fc);
        half8 gk0 = *(const half8*)(yb + pk0 * FF + fc);
        half8 gj1 = *(const half8*)(yb + pj1 * FF + fc);
        half8 gk1 = *(const half8*)(yb + pk1 * FF + fc);

        // 2. commit prefetched A -> LDS (f32 -> f16)
#pragma unroll
        for (int m = 0; m < 3; ++m) {
            a_tile[w][lofs2[m][0]] = (_Float16)pA[m].x;
            a_tile[w][lofs2[m][1]] = (_Float16)pA[m].y;
        }
        if (lane < 16) a_tile[w][tofs] = (_Float16)pT;

        // 3. prefetch next A tile (overlaps MFMA/ssp chain)
        if (it + 1 < NIT) {
            const int n0 = (split * 16 + (it + 1) * 4 + w) * 16;
            const float* dn = dbase + n0 * TH;
#pragma unroll
            for (int m = 0; m < 3; ++m) pA[m] = *(const float2*)(dn + m * 128 + lane * 2);
            if (lane < 16) pT = dn[384 + lane];
        }

        // interp weights for this tile's two row-groups (4 shfl + 4 splats)
        const __half2 wj0 = __float2half2_rn(__shfl(wjL, sl0));
        const __half2 wk0 = __float2half2_rn(__shfl(wkL, sl0));
        const __half2 wj1 = __float2half2_rn(__shfl(wjL, sl1));
        const __half2 wk1 = __float2half2_rn(__shfl(wkL, sl1));

        // 4. mm1 (swapped, permuted) + packed ssp — output stays in registers;
        //    permuted features make hh exactly mm2's B-frag in natural order
        half8 afrag = *(const half8*)&a_tile[w][l16 * ASTRIDE + quad * 8];
        __half2 hh[8];
#pragma unroll
        for (int g = 0; g < 4; ++g) {
            floatx4 hv = __builtin_amdgcn_mfma_f32_16x16x32_f16(B1[g], afrag, zero4, 0, 0, 0);
            hh[2 * g]     = ssp2(__hadd2(pk2(hv[0], hv[1]), b1p[g][0]));
            hh[2 * g + 1] = ssp2(__hadd2(pk2(hv[2], hv[3]), b1p[g][1]));
        }
        const half8 a2q0 = pack8(hh[0], hh[1], hh[2], hh[3]);
        const half8 a2q1 = pack8(hh[4], hh[5], hh[6], hh[7]);

        // 5. mm2 (K=64, swapped); single LDS transpose trip: native D layout
        //    (lane owns triple l16, feats g*16+quad*4+r) -> ds_write_b64,
        //    read back b128 in gather layout (safe: per-wave DS program order)
#pragma unroll
        for (int g = 0; g < 4; ++g) {
            floatx4 w2 = __builtin_amdgcn_mfma_f32_16x16x32_f16(B2[g][0], a2q0, zero4, 0, 0, 0);
            w2 = __builtin_amdgcn_mfma_f32_16x16x32_f16(B2[g][1], a2q1, w2, 0, 0, 0);
            __half2 f01 = pk2(w2[0] + b2f[g][0], w2[1] + b2f[g][1]);
            __half2 f23 = pk2(w2[2] + b2f[g][2], w2[3] + b2f[g][3]);
            *(half4v*)&f_tile[w][l16 * HSTRIDE + g * 16 + quad * 4] = pack4(f01, f23);
        }
        half8 f0 = *(const half8*)&f_tile[w][rA * HSTRIDE + fc];
        half8 f1 = *(const half8*)&f_tile[w][(8 + rA) * HSTRIDE + fc];

        // 6. epilogue: packed-f16 interp + filter-mul (2 terms only in f16),
        //    flushed to f32 accumulators every iteration
        const __half2* gj0p = (const __half2*)&gj0;
        const __half2* gk0p = (const __half2*)&gk0;
        const __half2* gj1p = (const __half2*)&gj1;
        const __half2* gk1p = (const __half2*)&gk1;
        const __half2* f0p = (const __half2*)&f0;
        const __half2* f1p = (const __half2*)&f1;
#pragma unroll
        for (int p = 0; p < 4; ++p) {
            __half2 fv0 = __hfma2(wj0, gj0p[p], __hmul2(wk0, gk0p[p]));
            __half2 fv1 = __hfma2(wj1, gj1p[p], __hmul2(wk1, gk1p[p]));
            __half2 tot = __hfma2(f1p[p], fv1, __hmul2(f0p[p], fv0));
            acc[2 * p]     += __low2float(tot);
            acc[2 * p + 1] += __high2float(tot);
        }
    }

    // ---- reduce over row-groups within wave ----
#pragma unroll
    for (int i = 0; i < 8; ++i) {
        acc[i] += __shfl_xor(acc[i], 8, 64);
        acc[i] += __shfl_xor(acc[i], 16, 64);
        acc[i] += __shfl_xor(acc[i], 32, 64);
    }
    if (lane < 8)
#pragma unroll
        for (int i = 0; i < 8; ++i) red[w][lane * 8 + i] = acc[i];
    __syncthreads();

    if (tid < FF)
        partial[(split * (BB * AA) + ba) * FF + tid] =
            red[0][tid] + red[1][tid] + red[2][tid] + red[3][tid];
}

// Kernel 3: sum the NSPLIT partials, f2out matvec + ssp
__global__ void out_kernel(const float* __restrict__ partial,
                           const float* __restrict__ Wf,
                           const float* __restrict__ bf,
                           float* __restrict__ out) {
    __shared__ float yag[FF];
    const int ba = blockIdx.x;
    const int t = threadIdx.x;  // 128
    if (t < FF) {
        float s = 0.f;
#pragma unroll
        for (int sp = 0; sp < NSPLIT; ++sp)
            s += partial[(sp * (BB * AA) + ba) * FF + t];
        yag[t] = s;
    }
    __syncthreads();
    float a = bf[t];
#pragma unroll 8
    for (int f = 0; f < FF; ++f) a += yag[f] * Wf[f * DOUT + t];
    out[(long)ba * DOUT + t] = ssp_f(a);
}

extern "C" void kernel_launch(void* const* d_in, const int* in_sizes, int n_in,
                              void* d_out, int out_size, void* d_ws, size_t ws_size,
                              hipStream_t stream) {
    const float* x       = (const float*)d_in[0];
    const float* r_ij    = (const float*)d_in[2];
    const float* r_ik    = (const float*)d_in[3];
    const int*   nbrj    = (const int*)d_in[7];
    const int*   nbrk    = (const int*)d_in[8];
    const float* tmask   = (const float*)d_in[9];
    const float* d_ijk   = (const float*)d_in[10];
    const float* W_in2f  = (const float*)d_in[11];
    const float* W_t1    = (const float*)d_in[12];
    const float* b_t1    = (const float*)d_in[13];
    const float* W_t2    = (const float*)d_in[14];
    const float* b_t2    = (const float*)d_in[15];
    const float* W_f2out = (const float*)d_in[16];
    const float* b_f2out = (const float*)d_in[17];
    float* out = (float*)d_out;

    char* ws = (char*)d_ws;
    _Float16* y      = (_Float16*)(ws + OFF_Y);
    float* partial   = (float*)(ws + OFF_PARTIAL);
    _Float16* B1tab  = (_Float16*)(ws + OFF_B1);
    _Float16* B2tab  = (_Float16*)(ws + OFF_B2);
    _Float16* B1Ptab = (_Float16*)(ws + OFF_B1P);
    float* B2Ftab    = (float*)(ws + OFF_B2F);

    in2f_prep_kernel<<<BB * AA, 64, 0, stream>>>(x, W_in2f, y, W_t1, b_t1,
                                                 W_t2, b_t2, B1tab, B2tab,
                                                 B1Ptab, B2Ftab);
    triple_kernel<<<BB * AA * NSPLIT, 256, 0, stream>>>(nbrj, nbrk, r_ij, r_ik,
                                                        tmask, d_ijk, B1tab, B2tab,
                                                        B1Ptab, B2Ftab, y, partial);
    out_kernel<<<BB * AA, 128, 0, stream>>>(partial, W_f2out, b_f2out, out);
}

// Round 4
// 248.151 us; speedup vs baseline: 1.1185x; 1.0088x over previous
//
#include <hip/hip_runtime.h>
#include <hip/hip_fp16.h>

#define BB 2
#define AA 512
#define NN 1024
#define FF 64
#define DIN 128
#define DOUT 128
#define TH 25
#define ASTRIDE 40   // halves per a_tile row (16B-aligned frag base)
#define HSTRIDE 72   // halves per f_tile row (16B-aligned, 144B row pitch)
#define NSPLIT 4
#define NIT 4        // tiles per wave (processed as 2 pairs, 2 streams in flight)

typedef _Float16 half8 __attribute__((ext_vector_type(8)));
typedef _Float16 half4v __attribute__((ext_vector_type(4)));
typedef float floatx4 __attribute__((ext_vector_type(4)));

__device__ __forceinline__ float ssp_f(float x) {
    return __logf(0.5f * __expf(x) + 0.5f);  // softplus(x) - ln2
}

__device__ __forceinline__ float cutcos(float r) {
    float c = 0.5f * (__cosf(r * (3.14159265358979323846f / 5.0f)) + 1.0f);
    return (r < 5.0f) ? c : 0.0f;
}

// packed-f16 shifted softplus on a half2 (v_exp_f16/v_log_f16 + pk ops)
__device__ __forceinline__ __half2 ssp2(__half2 x) {
    const __half2 hlf = __float2half2_rn(0.5f);
    return h2log(__hfma2(h2exp(x), hlf, hlf));
}

// pack two f32 -> __half2 (v_cvt_pkrtz_f16_f32); bit-cast through memory
__device__ __forceinline__ __half2 pk2(float a, float b) {
    auto v = __builtin_amdgcn_cvt_pkrtz(a, b);  // __fp16 ext_vector(2)
    __half2 r;
    __builtin_memcpy(&r, &v, sizeof(r));
    return r;
}

// pack two half2 -> 4 x f16 for a single ds_write_b64
__device__ __forceinline__ half4v pack4(__half2 lo, __half2 hi) {
    half4v r;
    __builtin_memcpy(&r, &lo, 4);
    __builtin_memcpy(reinterpret_cast<char*>(&r) + 4, &hi, 4);
    return r;
}

// pack four half2 -> half8 (register concat for MFMA operand)
__device__ __forceinline__ half8 pack8(__half2 a, __half2 b, __half2 c, __half2 d) {
    half8 r;
    __builtin_memcpy(reinterpret_cast<char*>(&r) + 0,  &a, 4);
    __builtin_memcpy(reinterpret_cast<char*>(&r) + 4,  &b, 4);
    __builtin_memcpy(reinterpret_cast<char*>(&r) + 8,  &c, 4);
    __builtin_memcpy(reinterpret_cast<char*>(&r) + 12, &d, 4);
    return r;
}

// ---- d_ws layout (bytes) ----
#define OFF_Y       0                                              // 128 KB
#define OFF_PARTIAL (OFF_Y + (size_t)BB * AA * FF * 2)             // 1 MB
#define OFF_B1      (OFF_PARTIAL + (size_t)NSPLIT * BB * AA * FF * 4)
#define OFF_B2      (OFF_B1 + 4 * 64 * 8 * 2)                      // B1tab 4 KB
#define OFF_BP      (OFF_B2 + 8 * 64 * 8 * 2)                      // B2tab 8 KB; BPtab 4 KB

// Kernel 1: in2f (all blocks) + weight-fragment prep (block 0 only).
// mm1 feature PERMUTATION: block g, D-row m -> feature base_g + 8*(m>>2) + (m&3),
// base = {0,4,32,36}. This makes mm1's per-lane D registers exactly mm2's
// B-operand fragment in natural f1 order (a2 built by register packing, no LDS).
__global__ void in2f_prep_kernel(const float* __restrict__ x,
                                 const float* __restrict__ Wi,
                                 _Float16* __restrict__ y,
                                 const float* __restrict__ W_t1, const float* __restrict__ b_t1,
                                 const float* __restrict__ W_t2, const float* __restrict__ b_t2,
                                 _Float16* __restrict__ B1tab, _Float16* __restrict__ B2tab,
                                 _Float16* __restrict__ BPtab) {
    __shared__ float xs[DIN];
    const int ba = blockIdx.x;
    const int t = threadIdx.x;  // 64
    xs[t] = x[ba * DIN + t];
    xs[t + 64] = x[ba * DIN + 64 + t];
    __syncthreads();
    float acc = 0.f;
#pragma unroll 8
    for (int d = 0; d < DIN; ++d) acc += xs[d] * Wi[d * FF + t];
    y[ba * FF + t] = (_Float16)acc;

    if (ba == 0) {
        const int lane = t, quad = t >> 4, l16 = t & 15;
        const int baseg[4] = {0, 4, 32, 36};
#pragma unroll
        for (int g = 0; g < 4; ++g) {
            // B1: A-operand row m=l16 of block g holds permuted feature
            const int feat_m = baseg[g] + 8 * (l16 >> 2) + (l16 & 3);
#pragma unroll
            for (int j = 0; j < 8; ++j) {
                int k = quad * 8 + j;
                B1tab[(g * 64 + lane) * 8 + j] =
                    (k < TH) ? (_Float16)W_t1[k * FF + feat_m] : (_Float16)0.f;
            }
            // bias pairs. b1 (permuted): D rows 4*quad+reg -> feat base_g+8*quad+reg
            // b2 (natural mm2 output): rows -> feat g*16+quad*4+reg
#pragma unroll
            for (int e = 0; e < 2; ++e) {
                BPtab[((g * 2 + e) * 64 + lane) * 2 + 0] =
                    (_Float16)b_t1[baseg[g] + 8 * quad + 2 * e];
                BPtab[((g * 2 + e) * 64 + lane) * 2 + 1] =
                    (_Float16)b_t1[baseg[g] + 8 * quad + 2 * e + 1];
                BPtab[1024 + ((g * 2 + e) * 64 + lane) * 2 + 0] =
                    (_Float16)b_t2[g * 16 + quad * 4 + 2 * e];
                BPtab[1024 + ((g * 2 + e) * 64 + lane) * 2 + 1] =
                    (_Float16)b_t2[g * 16 + quad * 4 + 2 * e + 1];
            }
            // B2 unchanged: k-dim (f1) in natural order matches permuted-mm1 output
#pragma unroll
            for (int q = 0; q < 2; ++q)
#pragma unroll
                for (int j = 0; j < 8; ++j)
                    B2tab[((g * 2 + q) * 64 + lane) * 8 + j] =
                        (_Float16)W_t2[(q * 32 + quad * 8 + j) * FF + g * 16 + l16];
        }
    }
}

// Kernel 2: TWO independent tile streams per wave (latency hiding via ILP).
// Per pair: both streams' gathers issue at top (8 b128 in flight), both A
// commits, then the two mm1->ssp->mm2->epilogue register chains interleave —
// while stream A waits on DS/MFMA, stream B issues. Register mm1->mm2 chain
// (feature permutation) keeps DS-pipe traffic at 12 ops/stream.
// NOTE: bare __launch_bounds__(256) — a (256,4) bound caps VGPRs at 64 and
// causes massive scratch spilling (measured: WRITE_SIZE 401 MB vs 1.5 MB legit).
__global__ __launch_bounds__(256) void triple_kernel(
    const int* __restrict__ nbrj, const int* __restrict__ nbrk,
    const float* __restrict__ r_ij, const float* __restrict__ r_ik,
    const float* __restrict__ tmask, const float* __restrict__ d_ijk,
    const _Float16* __restrict__ B1tab, const _Float16* __restrict__ B2tab,
    const _Float16* __restrict__ BPtab,
    const _Float16* __restrict__ y_tab, float* __restrict__ partial) {

    // per-wave, per-stream buffers -> no __syncthreads in main loop
    __shared__ __align__(16) _Float16 a_tile[4][2][16 * ASTRIDE];
    __shared__ __align__(16) _Float16 f_tile[4][2][16 * HSTRIDE];
    __shared__ float red[4][FF];

    const int blk = blockIdx.x;
    const int ba = blk >> 2;
    const int split = blk & 3;
    const int b = ba >> 9;  // A = 512
    const int tid = threadIdx.x;
    const int w = tid >> 6;
    const int lane = tid & 63;
    const int quad = lane >> 4;
    const int l16 = lane & 15;
    const int rA = lane >> 3;        // row group: rows rA and rA+8
    const int fc = (lane & 7) * 8;   // feature chunk base (8 f16)

    const long ban = (long)ba * NN;
    const float* dbase = d_ijk + (long)ba * NN * TH;
    const _Float16* yb = y_tab + (long)b * (AA * FF);

    // ---- weight fragments ----
    half8 B1[4];
    half8 B2[4][2];
    __half2 b1p[4][2], b2p[4][2];
#pragma unroll
    for (int g = 0; g < 4; ++g) {
        B1[g] = *(const half8*)(B1tab + (g * 64 + lane) * 8);
        B2[g][0] = *(const half8*)(B2tab + ((g * 2 + 0) * 64 + lane) * 8);
        B2[g][1] = *(const half8*)(B2tab + ((g * 2 + 1) * 64 + lane) * 8);
#pragma unroll
        for (int e = 0; e < 2; ++e) {
            b1p[g][e] = *(const __half2*)(BPtab + ((g * 2 + e) * 64 + lane) * 2);
            b2p[g][e] = *(const __half2*)(BPtab + 1024 + ((g * 2 + e) * 64 + lane) * 2);
        }
    }

    // ---- per-lane triple precompute: lane (quad,l16) owns triple l16 of the
    //      tile it==quad. Pairs fetch via shfl from lane it*16 + row.
    const int myn = (split * 16 + quad * 4 + w) * 16 + l16;
    const long myna = ban + myn;
    const float rijL = r_ij[myna], rikL = r_ik[myna];
    const float ivL = cutcos(rijL) * cutcos(rikL) * tmask[myna] / (rijL + rikL);
    const float wjL = rijL * ivL, wkL = rikL * ivL;
    const int pjL = nbrj[myna], pkL = nbrk[myna];

    // zero A-tile K-pad cols 25..31 once (both streams)
    for (int idx = lane; idx < 16 * 7; idx += 64) {
        int r = idx / 7, c = 25 + idx % 7;
        a_tile[w][0][r * ASTRIDE + c] = (_Float16)0.f;
        a_tile[w][1][r * ASTRIDE + c] = (_Float16)0.f;
    }

    // A staging map: 400 contiguous floats; 3 x float2/lane + 16-float tail
    int lofs2[3][2];
#pragma unroll
    for (int m = 0; m < 3; ++m)
#pragma unroll
        for (int e = 0; e < 2; ++e) {
            int s = m * 128 + lane * 2 + e;
            int r = s / TH, c = s - r * TH;
            lofs2[m][e] = r * ASTRIDE + c;
        }
    const int tofs = 15 * ASTRIDE + 9 + lane;  // tail: row 15 cols 9..24 (lane<16)

    float acc0[8], acc1[8];
#pragma unroll
    for (int i = 0; i < 8; ++i) { acc0[i] = 0.f; acc1[i] = 0.f; }
    const floatx4 zero4 = {0.f, 0.f, 0.f, 0.f};

    // ---- prologue: prefetch A for tiles 0,1 ----
    float2 pA0[3], pA1[3];
    float pT0 = 0.f, pT1 = 0.f;
    {
        const int n0 = (split * 16 + w) * 16;
        const float* d0 = dbase + (long)n0 * TH;
        const float* d1 = d0 + 4 * 16 * TH;  // next tile: +4*16 triples
#pragma unroll
        for (int m = 0; m < 3; ++m) {
            pA0[m] = *(const float2*)(d0 + m * 128 + lane * 2);
            pA1[m] = *(const float2*)(d1 + m * 128 + lane * 2);
        }
        if (lane < 16) { pT0 = d0[384 + lane]; pT1 = d1[384 + lane]; }
    }

#pragma unroll 1
    for (int pit = 0; pit < NIT / 2; ++pit) {
        const int t0 = pit * 2, t1 = t0 + 1;

        // 1. both streams' gather indices via shfl; issue 8 gathers up front
        const int sa0 = t0 * 16 + rA, sa1 = sa0 + 8;
        const int sb0 = t1 * 16 + rA, sb1 = sb0 + 8;
        const int pja0 = __shfl(pjL, sa0), pka0 = __shfl(pkL, sa0);
        const int pja1 = __shfl(pjL, sa1), pka1 = __shfl(pkL, sa1);
        const int pjb0 = __shfl(pjL, sb0), pkb0 = __shfl(pkL, sb0);
        const int pjb1 = __shfl(pjL, sb1), pkb1 = __shfl(pkL, sb1);
        half8 gja0 = *(const half8*)(yb + pja0 * FF + fc);
        half8 gka0 = *(const half8*)(yb + pka0 * FF + fc);
        half8 gja1 = *(const half8*)(yb + pja1 * FF + fc);
        half8 gka1 = *(const half8*)(yb + pka1 * FF + fc);
        half8 gjb0 = *(const half8*)(yb + pjb0 * FF + fc);
        half8 gkb0 = *(const half8*)(yb + pkb0 * FF + fc);
        half8 gjb1 = *(const half8*)(yb + pjb1 * FF + fc);
        half8 gkb1 = *(const half8*)(yb + pkb1 * FF + fc);

        // 2. commit prefetched A -> LDS, both streams (f32 -> f16)
#pragma unroll
        for (int m = 0; m < 3; ++m) {
            a_tile[w][0][lofs2[m][0]] = (_Float16)pA0[m].x;
            a_tile[w][0][lofs2[m][1]] = (_Float16)pA0[m].y;
            a_tile[w][1][lofs2[m][0]] = (_Float16)pA1[m].x;
            a_tile[w][1][lofs2[m][1]] = (_Float16)pA1[m].y;
        }
        if (lane < 16) {
            a_tile[w][0][tofs] = (_Float16)pT0;
            a_tile[w][1][tofs] = (_Float16)pT1;
        }

        // 3. prefetch next pair (overlaps both compute chains)
        if (pit + 1 < NIT / 2) {
            const int n0 = (split * 16 + (t0 + 2) * 4 + w) * 16;
            const float* d0 = dbase + (long)n0 * TH;
            const float* d1 = d0 + 4 * 16 * TH;
#pragma unroll
            for (int m = 0; m < 3; ++m) {
                pA0[m] = *(const float2*)(d0 + m * 128 + lane * 2);
                pA1[m] = *(const float2*)(d1 + m * 128 + lane * 2);
            }
            if (lane < 16) { pT0 = d0[384 + lane]; pT1 = d1[384 + lane]; }
        }

        // interp weights for both streams' row-groups
        const __half2 wja0 = __float2half2_rn(__shfl(wjL, sa0));
        const __half2 wka0 = __float2half2_rn(__shfl(wkL, sa0));
        const __half2 wja1 = __float2half2_rn(__shfl(wjL, sa1));
        const __half2 wka1 = __float2half2_rn(__shfl(wkL, sa1));
        const __half2 wjb0 = __float2half2_rn(__shfl(wjL, sb0));
        const __half2 wkb0 = __float2half2_rn(__shfl(wkL, sb0));
        const __half2 wjb1 = __float2half2_rn(__shfl(wjL, sb1));
        const __half2 wkb1 = __float2half2_rn(__shfl(wkL, sb1));

        // 4. mm1 + ssp, both streams interleaved (independent register chains)
        half8 afA = *(const half8*)&a_tile[w][0][l16 * ASTRIDE + quad * 8];
        half8 afB = *(const half8*)&a_tile[w][1][l16 * ASTRIDE + quad * 8];
        __half2 hhA[8], hhB[8];
#pragma unroll
        for (int g = 0; g < 4; ++g) {
            floatx4 hvA = __builtin_amdgcn_mfma_f32_16x16x32_f16(B1[g], afA, zero4, 0, 0, 0);
            floatx4 hvB = __builtin_amdgcn_mfma_f32_16x16x32_f16(B1[g], afB, zero4, 0, 0, 0);
            hhA[2 * g]     = ssp2(__hadd2(pk2(hvA[0], hvA[1]), b1p[g][0]));
            hhB[2 * g]     = ssp2(__hadd2(pk2(hvB[0], hvB[1]), b1p[g][0]));
            hhA[2 * g + 1] = ssp2(__hadd2(pk2(hvA[2], hvA[3]), b1p[g][1]));
            hhB[2 * g + 1] = ssp2(__hadd2(pk2(hvB[2], hvB[3]), b1p[g][1]));
        }
        const half8 a2A0 = pack8(hhA[0], hhA[1], hhA[2], hhA[3]);
        const half8 a2A1 = pack8(hhA[4], hhA[5], hhA[6], hhA[7]);
        const half8 a2B0 = pack8(hhB[0], hhB[1], hhB[2], hhB[3]);
        const half8 a2B1 = pack8(hhB[4], hhB[5], hhB[6], hhB[7]);

        // 5. mm2 (K=64) both streams; single LDS transpose trip each:
        //    native D layout (triple l16, feats g*16+quad*4+r) -> ds_write_b64,
        //    read back b128 in gather layout (per-wave DS program order)
#pragma unroll
        for (int g = 0; g < 4; ++g) {
            floatx4 w2A = __builtin_amdgcn_mfma_f32_16x16x32_f16(B2[g][0], a2A0, zero4, 0, 0, 0);
            floatx4 w2B = __builtin_amdgcn_mfma_f32_16x16x32_f16(B2[g][0], a2B0, zero4, 0, 0, 0);
            w2A = __builtin_amdgcn_mfma_f32_16x16x32_f16(B2[g][1], a2A1, w2A, 0, 0, 0);
            w2B = __builtin_amdgcn_mfma_f32_16x16x32_f16(B2[g][1], a2B1, w2B, 0, 0, 0);
            __half2 fA01 = __hadd2(pk2(w2A[0], w2A[1]), b2p[g][0]);
            __half2 fA23 = __hadd2(pk2(w2A[2], w2A[3]), b2p[g][1]);
            __half2 fB01 = __hadd2(pk2(w2B[0], w2B[1]), b2p[g][0]);
            __half2 fB23 = __hadd2(pk2(w2B[2], w2B[3]), b2p[g][1]);
            *(half4v*)&f_tile[w][0][l16 * HSTRIDE + g * 16 + quad * 4] = pack4(fA01, fA23);
            *(half4v*)&f_tile[w][1][l16 * HSTRIDE + g * 16 + quad * 4] = pack4(fB01, fB23);
        }
        half8 f0A = *(const half8*)&f_tile[w][0][rA * HSTRIDE + fc];
        half8 f1A = *(const half8*)&f_tile[w][0][(8 + rA) * HSTRIDE + fc];
        half8 f0B = *(const half8*)&f_tile[w][1][rA * HSTRIDE + fc];
        half8 f1B = *(const half8*)&f_tile[w][1][(8 + rA) * HSTRIDE + fc];

        // 6. epilogue, both streams, f32 accumulate
        {
            const __half2* gj0p = (const __half2*)&gja0;
            const __half2* gk0p = (const __half2*)&gka0;
            const __half2* gj1p = (const __half2*)&gja1;
            const __half2* gk1p = (const __half2*)&gka1;
            const __half2* f0p = (const __half2*)&f0A;
            const __half2* f1p = (const __half2*)&f1A;
#pragma unroll
            for (int p = 0; p < 4; ++p) {
                __half2 fv0 = __hfma2(wja0, gj0p[p], __hmul2(wka0, gk0p[p]));
                __half2 fv1 = __hfma2(wja1, gj1p[p], __hmul2(wka1, gk1p[p]));
                __half2 tot = __hfma2(f1p[p], fv1, __hmul2(f0p[p], fv0));
                acc0[2 * p]     += __low2float(tot);
                acc0[2 * p + 1] += __high2float(tot);
            }
        }
        {
            const __half2* gj0p = (const __half2*)&gjb0;
            const __half2* gk0p = (const __half2*)&gkb0;
            const __half2* gj1p = (const __half2*)&gjb1;
            const __half2* gk1p = (const __half2*)&gkb1;
            const __half2* f0p = (const __half2*)&f0B;
            const __half2* f1p = (const __half2*)&f1B;
#pragma unroll
            for (int p = 0; p < 4; ++p) {
                __half2 fv0 = __hfma2(wjb0, gj0p[p], __hmul2(wkb0, gk0p[p]));
                __half2 fv1 = __hfma2(wjb1, gj1p[p], __hmul2(wkb1, gk1p[p]));
                __half2 tot = __hfma2(f1p[p], fv1, __hmul2(f0p[p], fv0));
                acc1[2 * p]     += __low2float(tot);
                acc1[2 * p + 1] += __high2float(tot);
            }
        }
    }

    // ---- merge streams + reduce over row-groups within wave ----
    float accr[8];
#pragma unroll
    for (int i = 0; i < 8; ++i) {
        float a = acc0[i] + acc1[i];
        a += __shfl_xor(a, 8, 64);
        a += __shfl_xor(a, 16, 64);
        a += __shfl_xor(a, 32, 64);
        accr[i] = a;
    }
    if (lane < 8)
#pragma unroll
        for (int i = 0; i < 8; ++i) red[w][lane * 8 + i] = accr[i];
    __syncthreads();

    if (tid < FF)
        partial[(split * (BB * AA) + ba) * FF + tid] =
            red[0][tid] + red[1][tid] + red[2][tid] + red[3][tid];
}

// Kernel 3: sum the NSPLIT partials, f2out matvec + ssp
__global__ void out_kernel(const float* __restrict__ partial,
                           const float* __restrict__ Wf,
                           const float* __restrict__ bf,
                           float* __restrict__ out) {
    __shared__ float yag[FF];
    const int ba = blockIdx.x;
    const int t = threadIdx.x;  // 128
    if (t < FF) {
        float s = 0.f;
#pragma unroll
        for (int sp = 0; sp < NSPLIT; ++sp)
            s += partial[(sp * (BB * AA) + ba) * FF + t];
        yag[t] = s;
    }
    __syncthreads();
    float a = bf[t];
#pragma unroll 8
    for (int f = 0; f < FF; ++f) a += yag[f] * Wf[f * DOUT + t];
    out[(long)ba * DOUT + t] = ssp_f(a);
}

extern "C" void kernel_launch(void* const* d_in, const int* in_sizes, int n_in,
                              void* d_out, int out_size, void* d_ws, size_t ws_size,
                              hipStream_t stream) {
    const float* x       = (const float*)d_in[0];
    const float* r_ij    = (const float*)d_in[2];
    const float* r_ik    = (const float*)d_in[3];
    const int*   nbrj    = (const int*)d_in[7];
    const int*   nbrk    = (const int*)d_in[8];
    const float* tmask   = (const float*)d_in[9];
    const float* d_ijk   = (const float*)d_in[10];
    const float* W_in2f  = (const float*)d_in[11];
    const float* W_t1    = (const float*)d_in[12];
    const float* b_t1    = (const float*)d_in[13];
    const float* W_t2    = (const float*)d_in[14];
    const float* b_t2    = (const float*)d_in[15];
    const float* W_f2out = (const float*)d_in[16];
    const float* b_f2out = (const float*)d_in[17];
    float* out = (float*)d_out;

    char* ws = (char*)d_ws;
    _Float16* y      = (_Float16*)(ws + OFF_Y);
    float* partial   = (float*)(ws + OFF_PARTIAL);
    _Float16* B1tab  = (_Float16*)(ws + OFF_B1);
    _Float16* B2tab  = (_Float16*)(ws + OFF_B2);
    _Float16* BPtab  = (_Float16*)(ws + OFF_BP);

    in2f_prep_kernel<<<BB * AA, 64, 0, stream>>>(x, W_in2f, y, W_t1, b_t1,
                                                 W_t2, b_t2, B1tab, B2tab, BPtab);
    triple_kernel<<<BB * AA * NSPLIT, 256, 0, stream>>>(nbrj, nbrk, r_ij, r_ik,
                                                        tmask, d_ijk, B1tab, B2tab,
                                                        BPtab, y, partial);
    out_kernel<<<BB * AA, 128, 0, stream>>>(partial, W_f2out, b_f2out, out);
}

// Round 5
// 246.056 us; speedup vs baseline: 1.1281x; 1.0085x over previous
//
#include <hip/hip_runtime.h>
#include <hip/hip_fp16.h>

#define BB 2
#define AA 512
#define NN 1024
#define FF 64
#define DIN 128
#define DOUT 128
#define TH 25
#define ASTRIDE 40   // halves per a_tile row (16B-aligned frag base)
#define HSTRIDE 72   // halves per h_tile row (16B-aligned, 144B row pitch)
#define NSPLIT 8
#define NIT 2        // NN / (16 * 4 * NSPLIT) tiles per wave

typedef _Float16 half8 __attribute__((ext_vector_type(8)));
typedef _Float16 half4v __attribute__((ext_vector_type(4)));
typedef float floatx4 __attribute__((ext_vector_type(4)));

#define LOG2E 1.44269504088896f
#define LN2F  0.693147180559945f

__device__ __forceinline__ float ssp_f(float x) {
    return __logf(0.5f * __expf(x) + 0.5f);  // softplus(x) - ln2
}

__device__ __forceinline__ float cutcos(float r) {
    float c = 0.5f * (__cosf(r * (3.14159265358979323846f / 5.0f)) + 1.0f);
    return (r < 5.0f) ? c : 0.0f;
}

// folded shifted softplus: input z = a*log2e - 1 (scale/shift folded into W1/b1),
// output log2(0.5*e^a + 0.5) = ssp(a)/ln2 (ln2 folded into W2 rows).
// Only 2 trans + 1 add per half2 beyond the exp/log themselves.
__device__ __forceinline__ __half2 ssp2f(__half2 z) {
    const __half2 hlf = __float2half2_rn(0.5f);
    return h2log2(__hadd2(h2exp2(z), hlf));
}

// pack two f32 -> __half2 (v_cvt_pkrtz_f16_f32); bit-cast through memory
__device__ __forceinline__ __half2 pk2(float a, float b) {
    auto v = __builtin_amdgcn_cvt_pkrtz(a, b);  // __fp16 ext_vector(2)
    __half2 r;
    __builtin_memcpy(&r, &v, sizeof(r));
    return r;
}

// pack two half2 -> 4 x f16 for a single ds_write_b64
__device__ __forceinline__ half4v pack4(__half2 lo, __half2 hi) {
    half4v r;
    __builtin_memcpy(&r, &lo, 4);
    __builtin_memcpy(reinterpret_cast<char*>(&r) + 4, &hi, 4);
    return r;
}

// ---- d_ws layout (bytes) ----
#define OFF_Y       0                                              // 128 KB
#define OFF_PARTIAL (OFF_Y + (size_t)BB * AA * FF * 2)             // 2 MB (NSPLIT=8)
#define OFF_B1      (OFF_PARTIAL + (size_t)NSPLIT * BB * AA * FF * 4)
#define OFF_B2      (OFF_B1 + 4 * 64 * 8 * 2)                      // B1tab 4 KB
#define OFF_BP      (OFF_B2 + 8 * 64 * 8 * 2)                      // B2tab 8 KB; BPtab(b2) 2 KB

// Kernel 1: in2f (all blocks) + weight-fragment prep (block 0 only).
// Folds: W_t1 *= log2e; bias row k=25 of B1 = b_t1*log2e - 1 (A col 25 is 1.0),
// so mm1's f32 accumulator directly yields z for ssp2f. W_t2 *= ln2 restores scale.
__global__ void in2f_prep_kernel(const float* __restrict__ x,
                                 const float* __restrict__ Wi,
                                 _Float16* __restrict__ y,
                                 const float* __restrict__ W_t1, const float* __restrict__ b_t1,
                                 const float* __restrict__ W_t2, const float* __restrict__ b_t2,
                                 _Float16* __restrict__ B1tab, _Float16* __restrict__ B2tab,
                                 _Float16* __restrict__ BPtab) {
    __shared__ float xs[DIN];
    const int ba = blockIdx.x;
    const int t = threadIdx.x;  // 64
    xs[t] = x[ba * DIN + t];
    xs[t + 64] = x[ba * DIN + 64 + t];
    __syncthreads();
    float acc = 0.f;
#pragma unroll 8
    for (int d = 0; d < DIN; ++d) acc += xs[d] * Wi[d * FF + t];
    y[ba * FF + t] = (_Float16)acc;

    if (ba == 0) {  // prep: format MFMA fragments in per-lane layout
        const int lane = t, quad = t >> 4, l16 = t & 15;
#pragma unroll
        for (int g = 0; g < 4; ++g) {
            const int featA = g * 16 + l16;  // A-operand (M) feature of row l16
#pragma unroll
            for (int j = 0; j < 8; ++j) {
                int k = quad * 8 + j;
                _Float16 v;
                if (k < TH)       v = (_Float16)(W_t1[k * FF + featA] * LOG2E);
                else if (k == TH) v = (_Float16)(b_t1[featA] * LOG2E - 1.0f);  // bias row (A col 25 = 1)
                else              v = (_Float16)0.f;
                B1tab[(g * 64 + lane) * 8 + j] = v;
            }
            // b2 pairs: D rows 4*quad+{2e,2e+1} -> feature g*16+quad*4+...
#pragma unroll
            for (int e = 0; e < 2; ++e) {
                BPtab[((g * 2 + e) * 64 + lane) * 2 + 0] =
                    (_Float16)b_t2[g * 16 + quad * 4 + 2 * e];
                BPtab[((g * 2 + e) * 64 + lane) * 2 + 1] =
                    (_Float16)b_t2[g * 16 + quad * 4 + 2 * e + 1];
            }
            // B2 rows scaled by ln2 (h is stored as ssp/ln2)
#pragma unroll
            for (int q = 0; q < 2; ++q)
#pragma unroll
                for (int j = 0; j < 8; ++j)
                    B2tab[((g * 2 + q) * 64 + lane) * 8 + j] =
                        (_Float16)(W_t2[(q * 32 + quad * 8 + j) * FF + g * 16 + l16] * LN2F);
        }
    }
}

// Kernel 2: per-(ba,split) partial of the triple MLP + gather/interp aggregation.
// R1 structure (best measured) with NSPLIT=8/NIT=2: halve each wave's serial
// chain, double wave count, per-block LDS unchanged (the R4 mistake avoided).
// NOTE: bare __launch_bounds__(256) — a (256,4) bound caps VGPRs at 64 and
// causes massive scratch spilling (measured: WRITE_SIZE 401 MB vs 1.5 MB legit).
__global__ __launch_bounds__(256) void triple_kernel(
    const int* __restrict__ nbrj, const int* __restrict__ nbrk,
    const float* __restrict__ r_ij, const float* __restrict__ r_ik,
    const float* __restrict__ tmask, const float* __restrict__ d_ijk,
    const _Float16* __restrict__ B1tab, const _Float16* __restrict__ B2tab,
    const _Float16* __restrict__ BPtab,
    const _Float16* __restrict__ y_tab, float* __restrict__ partial) {

    // per-wave buffers -> no __syncthreads in main loop (same-wave DS is in-order)
    __shared__ __align__(16) _Float16 a_tile[4][16 * ASTRIDE];
    __shared__ __align__(16) _Float16 h_tile[4][16 * HSTRIDE];  // h, then reused for filter
    __shared__ float red[4][FF];

    const int blk = blockIdx.x;
    const int ba = blk >> 3;         // NSPLIT = 8
    const int split = blk & 7;
    const int b = ba >> 9;  // A = 512
    const int tid = threadIdx.x;
    const int w = tid >> 6;
    const int lane = tid & 63;
    const int quad = lane >> 4;
    const int l16 = lane & 15;
    const int rA = lane >> 3;        // row group: rows rA and rA+8
    const int fc = (lane & 7) * 8;   // feature chunk base (8 f16)

    const long ban = (long)ba * NN;
    const float* dbase = d_ijk + (long)ba * NN * TH;
    const _Float16* yb = y_tab + (long)b * (AA * FF);

    // ---- weight fragments: pre-formatted vector loads; b2 pairs as half2 ----
    half8 B1[4];
    half8 B2[4][2];
    __half2 b2p[4][2];
#pragma unroll
    for (int g = 0; g < 4; ++g) {
        B1[g] = *(const half8*)(B1tab + (g * 64 + lane) * 8);
        B2[g][0] = *(const half8*)(B2tab + ((g * 2 + 0) * 64 + lane) * 8);
        B2[g][1] = *(const half8*)(B2tab + ((g * 2 + 1) * 64 + lane) * 8);
#pragma unroll
        for (int e = 0; e < 2; ++e)
            b2p[g][e] = *(const __half2*)(BPtab + ((g * 2 + e) * 64 + lane) * 2);
    }

    // ---- per-lane triple precompute: lane (quad,l16) owns triple l16 of the
    //      tile it==(quad&1) (quads 2,3 duplicate 0,1 — NIT=2 only uses lanes
    //      0..31 as shfl sources). Coalesced one-shot loads, cutoffs once.
    const int myn = (split * 8 + (quad & 1) * 4 + w) * 16 + l16;
    const long myna = ban + myn;
    const float rijL = r_ij[myna], rikL = r_ik[myna];
    const float ivL = cutcos(rijL) * cutcos(rikL) * tmask[myna] / (rijL + rikL);
    const float wjL = rijL * ivL, wkL = rikL * ivL;
    const int pjL = nbrj[myna], pkL = nbrk[myna];

    // A-tile K-pad: col 25 = 1.0 (bias row), cols 26..31 = 0 — written once
    for (int idx = lane; idx < 16 * 7; idx += 64) {
        int r = idx / 7, c = 25 + idx % 7;
        a_tile[w][r * ASTRIDE + c] = (c == 25) ? (_Float16)1.f : (_Float16)0.f;
    }

    // A staging map: 400 contiguous floats; 3 x float2/lane + 16-float tail
    int lofs2[3][2];
#pragma unroll
    for (int m = 0; m < 3; ++m)
#pragma unroll
        for (int e = 0; e < 2; ++e) {
            int s = m * 128 + lane * 2 + e;
            int r = s / TH, c = s - r * TH;
            lofs2[m][e] = r * ASTRIDE + c;
        }
    const int tofs = 15 * ASTRIDE + 9 + lane;  // tail: row 15 cols 9..24 (lane<16)

    float acc[8];
#pragma unroll
    for (int i = 0; i < 8; ++i) acc[i] = 0.f;
    const floatx4 zero4 = {0.f, 0.f, 0.f, 0.f};

    // ---- prologue: prefetch A tile for it=0 ----
    float2 pA[3];
    float pT = 0.f;
    {
        const int n0 = (split * 8 + w) * 16;
        const float* dsrc = dbase + (long)n0 * TH;
#pragma unroll
        for (int m = 0; m < 3; ++m) pA[m] = *(const float2*)(dsrc + m * 128 + lane * 2);
        if (lane < 16) pT = dsrc[384 + lane];
    }

#pragma unroll 1
    for (int it = 0; it < NIT; ++it) {
        // 1. indices via cross-lane broadcast; issue gathers immediately
        const int sl0 = it * 16 + rA;   // lane holding triple n0+rA
        const int sl1 = sl0 + 8;        // lane holding triple n0+rA+8
        const int pj0 = __shfl(pjL, sl0), pk0 = __shfl(pkL, sl0);
        const int pj1 = __shfl(pjL, sl1), pk1 = __shfl(pkL, sl1);
        half8 gj0 = *(const half8*)(yb + pj0 * FF + fc);
        half8 gk0 = *(const half8*)(yb + pk0 * FF + fc);
        half8 gj1 = *(const half8*)(yb + pj1 * FF + fc);
        half8 gk1 = *(const half8*)(yb + pk1 * FF + fc);

        // 2. commit prefetched A -> LDS (f32 -> f16)
#pragma unroll
        for (int m = 0; m < 3; ++m) {
            a_tile[w][lofs2[m][0]] = (_Float16)pA[m].x;
            a_tile[w][lofs2[m][1]] = (_Float16)pA[m].y;
        }
        if (lane < 16) a_tile[w][tofs] = (_Float16)pT;

        // 3. prefetch next A tile (overlaps MFMA/ssp chain)
        if (it + 1 < NIT) {
            const int n0 = (split * 8 + (it + 1) * 4 + w) * 16;
            const float* dn = dbase + (long)n0 * TH;
#pragma unroll
            for (int m = 0; m < 3; ++m) pA[m] = *(const float2*)(dn + m * 128 + lane * 2);
            if (lane < 16) pT = dn[384 + lane];
        }

        // interp weights for this tile's two row-groups (4 shfl + 4 splats)
        const __half2 wj0 = __float2half2_rn(__shfl(wjL, sl0));
        const __half2 wk0 = __float2half2_rn(__shfl(wkL, sl0));
        const __half2 wj1 = __float2half2_rn(__shfl(wjL, sl1));
        const __half2 wk1 = __float2half2_rn(__shfl(wkL, sl1));

        // 4. mm1 (swapped; bias+log2e folded into B1) + folded packed ssp
        half8 afrag = *(const half8*)&a_tile[w][l16 * ASTRIDE + quad * 8];
#pragma unroll
        for (int g = 0; g < 4; ++g) {
            floatx4 hv = __builtin_amdgcn_mfma_f32_16x16x32_f16(B1[g], afrag, zero4, 0, 0, 0);
            __half2 h01 = ssp2f(pk2(hv[0], hv[1]));
            __half2 h23 = ssp2f(pk2(hv[2], hv[3]));
            *(half4v*)&h_tile[w][l16 * HSTRIDE + g * 16 + quad * 4] = pack4(h01, h23);
        }

        // 5. mm2 (K=64, swapped; W2 pre-scaled by ln2); filter written back into
        //    h_tile (safe: per-wave DS program order), read back in gather layout
        half8 a2q0 = *(const half8*)&h_tile[w][l16 * HSTRIDE + quad * 8];
        half8 a2q1 = *(const half8*)&h_tile[w][l16 * HSTRIDE + 32 + quad * 8];
#pragma unroll
        for (int g = 0; g < 4; ++g) {
            floatx4 w2 = __builtin_amdgcn_mfma_f32_16x16x32_f16(B2[g][0], a2q0, zero4, 0, 0, 0);
            w2 = __builtin_amdgcn_mfma_f32_16x16x32_f16(B2[g][1], a2q1, w2, 0, 0, 0);
            __half2 f01 = __hadd2(pk2(w2[0], w2[1]), b2p[g][0]);
            __half2 f23 = __hadd2(pk2(w2[2], w2[3]), b2p[g][1]);
            *(half4v*)&h_tile[w][l16 * HSTRIDE + g * 16 + quad * 4] = pack4(f01, f23);
        }
        half8 f0 = *(const half8*)&h_tile[w][rA * HSTRIDE + fc];
        half8 f1 = *(const half8*)&h_tile[w][(8 + rA) * HSTRIDE + fc];

        // 6. epilogue: packed-f16 interp + filter-mul (2 terms only in f16),
        //    flushed to f32 accumulators every iteration
        const __half2* gj0p = (const __half2*)&gj0;
        const __half2* gk0p = (const __half2*)&gk0;
        const __half2* gj1p = (const __half2*)&gj1;
        const __half2* gk1p = (const __half2*)&gk1;
        const __half2* f0p = (const __half2*)&f0;
        const __half2* f1p = (const __half2*)&f1;
#pragma unroll
        for (int p = 0; p < 4; ++p) {
            __half2 fv0 = __hfma2(wj0, gj0p[p], __hmul2(wk0, gk0p[p]));
            __half2 fv1 = __hfma2(wj1, gj1p[p], __hmul2(wk1, gk1p[p]));
            __half2 tot = __hfma2(f1p[p], fv1, __hmul2(f0p[p], fv0));
            acc[2 * p]     += __low2float(tot);
            acc[2 * p + 1] += __high2float(tot);
        }
    }

    // ---- reduce over row-groups within wave ----
#pragma unroll
    for (int i = 0; i < 8; ++i) {
        acc[i] += __shfl_xor(acc[i], 8, 64);
        acc[i] += __shfl_xor(acc[i], 16, 64);
        acc[i] += __shfl_xor(acc[i], 32, 64);
    }
    if (lane < 8)
#pragma unroll
        for (int i = 0; i < 8; ++i) red[w][lane * 8 + i] = acc[i];
    __syncthreads();

    if (tid < FF)
        partial[(split * (BB * AA) + ba) * FF + tid] =
            red[0][tid] + red[1][tid] + red[2][tid] + red[3][tid];
}

// Kernel 3: sum the NSPLIT partials, f2out matvec + ssp
__global__ void out_kernel(const float* __restrict__ partial,
                           const float* __restrict__ Wf,
                           const float* __restrict__ bf,
                           float* __restrict__ out) {
    __shared__ float yag[FF];
    const int ba = blockIdx.x;
    const int t = threadIdx.x;  // 128
    if (t < FF) {
        float s = 0.f;
#pragma unroll
        for (int sp = 0; sp < NSPLIT; ++sp)
            s += partial[(sp * (BB * AA) + ba) * FF + t];
        yag[t] = s;
    }
    __syncthreads();
    float a = bf[t];
#pragma unroll 8
    for (int f = 0; f < FF; ++f) a += yag[f] * Wf[f * DOUT + t];
    out[(long)ba * DOUT + t] = ssp_f(a);
}

extern "C" void kernel_launch(void* const* d_in, const int* in_sizes, int n_in,
                              void* d_out, int out_size, void* d_ws, size_t ws_size,
                              hipStream_t stream) {
    const float* x       = (const float*)d_in[0];
    const float* r_ij    = (const float*)d_in[2];
    const float* r_ik    = (const float*)d_in[3];
    const int*   nbrj    = (const int*)d_in[7];
    const int*   nbrk    = (const int*)d_in[8];
    const float* tmask   = (const float*)d_in[9];
    const float* d_ijk   = (const float*)d_in[10];
    const float* W_in2f  = (const float*)d_in[11];
    const float* W_t1    = (const float*)d_in[12];
    const float* b_t1    = (const float*)d_in[13];
    const float* W_t2    = (const float*)d_in[14];
    const float* b_t2    = (const float*)d_in[15];
    const float* W_f2out = (const float*)d_in[16];
    const float* b_f2out = (const float*)d_in[17];
    float* out = (float*)d_out;

    char* ws = (char*)d_ws;
    _Float16* y      = (_Float16*)(ws + OFF_Y);
    float* partial   = (float*)(ws + OFF_PARTIAL);
    _Float16* B1tab  = (_Float16*)(ws + OFF_B1);
    _Float16* B2tab  = (_Float16*)(ws + OFF_B2);
    _Float16* BPtab  = (_Float16*)(ws + OFF_BP);

    in2f_prep_kernel<<<BB * AA, 64, 0, stream>>>(x, W_in2f, y, W_t1, b_t1,
                                                 W_t2, b_t2, B1tab, B2tab, BPtab);
    triple_kernel<<<BB * AA * NSPLIT, 256, 0, stream>>>(nbrj, nbrk, r_ij, r_ik,
                                                        tmask, d_ijk, B1tab, B2tab,
                                                        BPtab, y, partial);
    out_kernel<<<BB * AA, 128, 0, stream>>>(partial, W_f2out, b_f2out, out);
}

// Round 6
// 234.039 us; speedup vs baseline: 1.1860x; 1.0513x over previous
//
#include <hip/hip_runtime.h>
#include <hip/hip_fp16.h>

#define BB 2
#define AA 512
#define NN 1024
#define FF 64
#define DIN 128
#define DOUT 128
#define TH 25
#define ASTRIDE 40   // halves per a_tile row (16B-aligned frag base)
#define HSTRIDE 72   // halves per h_tile row (16B-aligned, 144B row pitch)
#define NSPLIT 2
#define NIT 8        // NN / (16 * 4 * NSPLIT) tiles per wave

typedef _Float16 half8 __attribute__((ext_vector_type(8)));
typedef _Float16 half4v __attribute__((ext_vector_type(4)));
typedef float floatx4 __attribute__((ext_vector_type(4)));

#define LOG2E 1.44269504088896f
#define LN2F  0.693147180559945f

__device__ __forceinline__ float ssp_f(float x) {
    return __logf(0.5f * __expf(x) + 0.5f);  // softplus(x) - ln2
}

__device__ __forceinline__ float cutcos(float r) {
    float c = 0.5f * (__cosf(r * (3.14159265358979323846f / 5.0f)) + 1.0f);
    return (r < 5.0f) ? c : 0.0f;
}

// folded shifted softplus: input z = a*log2e - 1 (scale/shift folded into W1/b1),
// output log2(0.5*e^a + 0.5) = ssp(a)/ln2 (ln2 folded into W2 rows).
__device__ __forceinline__ __half2 ssp2f(__half2 z) {
    const __half2 hlf = __float2half2_rn(0.5f);
    return h2log2(__hadd2(h2exp2(z), hlf));
}

// pack two f32 -> __half2 (v_cvt_pkrtz_f16_f32); bit-cast through memory
__device__ __forceinline__ __half2 pk2(float a, float b) {
    auto v = __builtin_amdgcn_cvt_pkrtz(a, b);  // __fp16 ext_vector(2)
    __half2 r;
    __builtin_memcpy(&r, &v, sizeof(r));
    return r;
}

// pack two half2 -> 4 x f16 for a single ds_write_b64
__device__ __forceinline__ half4v pack4(__half2 lo, __half2 hi) {
    half4v r;
    __builtin_memcpy(&r, &lo, 4);
    __builtin_memcpy(reinterpret_cast<char*>(&r) + 4, &hi, 4);
    return r;
}

// ---- d_ws layout (bytes) ----
#define OFF_Y       0                                              // 128 KB
#define OFF_PARTIAL (OFF_Y + (size_t)BB * AA * FF * 2)             // 512 KB (NSPLIT=2)
#define OFF_B1      (OFF_PARTIAL + (size_t)NSPLIT * BB * AA * FF * 4)
#define OFF_B2      (OFF_B1 + 4 * 64 * 8 * 2)                      // B1tab 4 KB
#define OFF_BP      (OFF_B2 + 8 * 64 * 8 * 2)                      // B2tab 8 KB; BPtab(b2) 2 KB

// Kernel 1: in2f (all blocks) + weight-fragment prep (block 0 only).
// Folds: W_t1 *= log2e; bias row k=25 of B1 = b_t1*log2e - 1 (A col 25 is 1.0),
// so mm1's f32 accumulator directly yields z for ssp2f. W_t2 *= ln2 restores scale.
__global__ void in2f_prep_kernel(const float* __restrict__ x,
                                 const float* __restrict__ Wi,
                                 _Float16* __restrict__ y,
                                 const float* __restrict__ W_t1, const float* __restrict__ b_t1,
                                 const float* __restrict__ W_t2, const float* __restrict__ b_t2,
                                 _Float16* __restrict__ B1tab, _Float16* __restrict__ B2tab,
                                 _Float16* __restrict__ BPtab) {
    __shared__ float xs[DIN];
    const int ba = blockIdx.x;
    const int t = threadIdx.x;  // 64
    xs[t] = x[ba * DIN + t];
    xs[t + 64] = x[ba * DIN + 64 + t];
    __syncthreads();
    float acc = 0.f;
#pragma unroll 8
    for (int d = 0; d < DIN; ++d) acc += xs[d] * Wi[d * FF + t];
    y[ba * FF + t] = (_Float16)acc;

    if (ba == 0) {  // prep: format MFMA fragments in per-lane layout
        const int lane = t, quad = t >> 4, l16 = t & 15;
#pragma unroll
        for (int g = 0; g < 4; ++g) {
            const int featA = g * 16 + l16;  // A-operand (M) feature of row l16
#pragma unroll
            for (int j = 0; j < 8; ++j) {
                int k = quad * 8 + j;
                _Float16 v;
                if (k < TH)       v = (_Float16)(W_t1[k * FF + featA] * LOG2E);
                else if (k == TH) v = (_Float16)(b_t1[featA] * LOG2E - 1.0f);  // bias row (A col 25 = 1)
                else              v = (_Float16)0.f;
                B1tab[(g * 64 + lane) * 8 + j] = v;
            }
            // b2 pairs: D rows 4*quad+{2e,2e+1} -> feature g*16+quad*4+...
#pragma unroll
            for (int e = 0; e < 2; ++e) {
                BPtab[((g * 2 + e) * 64 + lane) * 2 + 0] =
                    (_Float16)b_t2[g * 16 + quad * 4 + 2 * e];
                BPtab[((g * 2 + e) * 64 + lane) * 2 + 1] =
                    (_Float16)b_t2[g * 16 + quad * 4 + 2 * e + 1];
            }
            // B2 rows scaled by ln2 (h is stored as ssp/ln2)
#pragma unroll
            for (int q = 0; q < 2; ++q)
#pragma unroll
                for (int j = 0; j < 8; ++j)
                    B2tab[((g * 2 + q) * 64 + lane) * 8 + j] =
                        (_Float16)(W_t2[(q * 32 + quad * 8 + j) * FF + g * 16 + l16] * LN2F);
        }
    }
}

// Kernel 2: per-(ba,split) partial of the triple MLP + gather/interp aggregation.
// NSPLIT=2 / NIT=8: per-wave fixed cost (weight loads, precompute, reduce)
// amortized over 8 iterations (R5's 2-iter waves paid it 4x as often).
// Per-lane precompute carries TWO triple sets (tiles 0..3 and 4..7).
// NOTE: bare __launch_bounds__(256) — a (256,4) bound caps VGPRs at 64 and
// causes massive scratch spilling (measured: WRITE_SIZE 401 MB vs 1.5 MB legit).
__global__ __launch_bounds__(256) void triple_kernel(
    const int* __restrict__ nbrj, const int* __restrict__ nbrk,
    const float* __restrict__ r_ij, const float* __restrict__ r_ik,
    const float* __restrict__ tmask, const float* __restrict__ d_ijk,
    const _Float16* __restrict__ B1tab, const _Float16* __restrict__ B2tab,
    const _Float16* __restrict__ BPtab,
    const _Float16* __restrict__ y_tab, float* __restrict__ partial) {

    // per-wave buffers -> no __syncthreads in main loop (same-wave DS is in-order)
    __shared__ __align__(16) _Float16 a_tile[4][16 * ASTRIDE];
    __shared__ __align__(16) _Float16 h_tile[4][16 * HSTRIDE];  // h, then reused for filter
    __shared__ float red[4][FF];

    const int blk = blockIdx.x;
    const int ba = blk >> 1;         // NSPLIT = 2
    const int split = blk & 1;
    const int b = ba >> 9;  // A = 512
    const int tid = threadIdx.x;
    const int w = tid >> 6;
    const int lane = tid & 63;
    const int quad = lane >> 4;
    const int l16 = lane & 15;
    const int rA = lane >> 3;        // row group: rows rA and rA+8
    const int fc = (lane & 7) * 8;   // feature chunk base (8 f16)

    const long ban = (long)ba * NN;
    const float* dbase = d_ijk + (long)ba * NN * TH;
    const _Float16* yb = y_tab + (long)b * (AA * FF);

    // ---- weight fragments: pre-formatted vector loads; b2 pairs as half2 ----
    half8 B1[4];
    half8 B2[4][2];
    __half2 b2p[4][2];
#pragma unroll
    for (int g = 0; g < 4; ++g) {
        B1[g] = *(const half8*)(B1tab + (g * 64 + lane) * 8);
        B2[g][0] = *(const half8*)(B2tab + ((g * 2 + 0) * 64 + lane) * 8);
        B2[g][1] = *(const half8*)(B2tab + ((g * 2 + 1) * 64 + lane) * 8);
#pragma unroll
        for (int e = 0; e < 2; ++e)
            b2p[g][e] = *(const __half2*)(BPtab + ((g * 2 + e) * 64 + lane) * 2);
    }

    // ---- per-lane triple precompute, TWO sets:
    //      set0: lane (quad,l16) owns triple l16 of tile (split*32 + quad*4 + w)
    //             (= the tile this wave runs at it==quad)
    //      set1: same for it==quad+4 (tile index +16, triple index +256)
    const int tile0 = split * 32 + quad * 4 + w;
    const long n0a = ban + (long)tile0 * 16 + l16;
    const long n1a = n0a + 256;
    const float rij0 = r_ij[n0a], rik0 = r_ik[n0a];
    const float rij1 = r_ij[n1a], rik1 = r_ik[n1a];
    const float iv0 = cutcos(rij0) * cutcos(rik0) * tmask[n0a] / (rij0 + rik0);
    const float iv1 = cutcos(rij1) * cutcos(rik1) * tmask[n1a] / (rij1 + rik1);
    const float wjL0 = rij0 * iv0, wkL0 = rik0 * iv0;
    const float wjL1 = rij1 * iv1, wkL1 = rik1 * iv1;
    const int pjL0 = nbrj[n0a], pkL0 = nbrk[n0a];
    const int pjL1 = nbrj[n1a], pkL1 = nbrk[n1a];

    // A-tile K-pad: col 25 = 1.0 (bias row), cols 26..31 = 0 — written once
    for (int idx = lane; idx < 16 * 7; idx += 64) {
        int r = idx / 7, c = 25 + idx % 7;
        a_tile[w][r * ASTRIDE + c] = (c == 25) ? (_Float16)1.f : (_Float16)0.f;
    }

    // A staging map: 400 contiguous floats; 3 x float2/lane + 16-float tail
    int lofs2[3][2];
#pragma unroll
    for (int m = 0; m < 3; ++m)
#pragma unroll
        for (int e = 0; e < 2; ++e) {
            int s = m * 128 + lane * 2 + e;
            int r = s / TH, c = s - r * TH;
            lofs2[m][e] = r * ASTRIDE + c;
        }
    const int tofs = 15 * ASTRIDE + 9 + lane;  // tail: row 15 cols 9..24 (lane<16)

    float acc[8];
#pragma unroll
    for (int i = 0; i < 8; ++i) acc[i] = 0.f;
    const floatx4 zero4 = {0.f, 0.f, 0.f, 0.f};

    // ---- prologue: prefetch A tile for it=0 ----
    float2 pA[3];
    float pT = 0.f;
    const float* dp0 = dbase + (long)(split * 32 + w) * 16 * TH;
    {
#pragma unroll
        for (int m = 0; m < 3; ++m) pA[m] = *(const float2*)(dp0 + m * 128 + lane * 2);
        if (lane < 16) pT = dp0[384 + lane];
    }

#pragma unroll 1
    for (int it = 0; it < NIT; ++it) {
        // 1. indices via cross-lane broadcast (set-select + bpermute)
        const bool s1 = (it >= 4);
        const int sl0 = (it & 3) * 16 + rA;   // lane holding triple n0+rA
        const int sl1 = sl0 + 8;              // lane holding triple n0+rA+8
        const int pjS = s1 ? pjL1 : pjL0, pkS = s1 ? pkL1 : pkL0;
        const float wjS = s1 ? wjL1 : wjL0, wkS = s1 ? wkL1 : wkL0;
        const int pj0 = __shfl(pjS, sl0), pk0 = __shfl(pkS, sl0);
        const int pj1 = __shfl(pjS, sl1), pk1 = __shfl(pkS, sl1);
        half8 gj0 = *(const half8*)(yb + pj0 * FF + fc);
        half8 gk0 = *(const half8*)(yb + pk0 * FF + fc);
        half8 gj1 = *(const half8*)(yb + pj1 * FF + fc);
        half8 gk1 = *(const half8*)(yb + pk1 * FF + fc);

        // 2. commit prefetched A -> LDS (f32 -> f16)
#pragma unroll
        for (int m = 0; m < 3; ++m) {
            a_tile[w][lofs2[m][0]] = (_Float16)pA[m].x;
            a_tile[w][lofs2[m][1]] = (_Float16)pA[m].y;
        }
        if (lane < 16) a_tile[w][tofs] = (_Float16)pT;

        // 3. prefetch next A tile (overlaps MFMA/ssp chain); +4 tiles = +1600 floats
        if (it + 1 < NIT) {
            const float* dn = dp0 + (it + 1) * 1600;
#pragma unroll
            for (int m = 0; m < 3; ++m) pA[m] = *(const float2*)(dn + m * 128 + lane * 2);
            if (lane < 16) pT = dn[384 + lane];
        }

        // interp weights for this tile's two row-groups (4 shfl + 4 splats)
        const __half2 wj0 = __float2half2_rn(__shfl(wjS, sl0));
        const __half2 wk0 = __float2half2_rn(__shfl(wkS, sl0));
        const __half2 wj1 = __float2half2_rn(__shfl(wjS, sl1));
        const __half2 wk1 = __float2half2_rn(__shfl(wkS, sl1));

        // 4. mm1 (swapped; bias+log2e folded into B1) + folded packed ssp
        half8 afrag = *(const half8*)&a_tile[w][l16 * ASTRIDE + quad * 8];
#pragma unroll
        for (int g = 0; g < 4; ++g) {
            floatx4 hv = __builtin_amdgcn_mfma_f32_16x16x32_f16(B1[g], afrag, zero4, 0, 0, 0);
            __half2 h01 = ssp2f(pk2(hv[0], hv[1]));
            __half2 h23 = ssp2f(pk2(hv[2], hv[3]));
            *(half4v*)&h_tile[w][l16 * HSTRIDE + g * 16 + quad * 4] = pack4(h01, h23);
        }

        // 5. mm2 (K=64, swapped; W2 pre-scaled by ln2); filter written back into
        //    h_tile (safe: per-wave DS program order), read back in gather layout
        half8 a2q0 = *(const half8*)&h_tile[w][l16 * HSTRIDE + quad * 8];
        half8 a2q1 = *(const half8*)&h_tile[w][l16 * HSTRIDE + 32 + quad * 8];
#pragma unroll
        for (int g = 0; g < 4; ++g) {
            floatx4 w2 = __builtin_amdgcn_mfma_f32_16x16x32_f16(B2[g][0], a2q0, zero4, 0, 0, 0);
            w2 = __builtin_amdgcn_mfma_f32_16x16x32_f16(B2[g][1], a2q1, w2, 0, 0, 0);
            __half2 f01 = __hadd2(pk2(w2[0], w2[1]), b2p[g][0]);
            __half2 f23 = __hadd2(pk2(w2[2], w2[3]), b2p[g][1]);
            *(half4v*)&h_tile[w][l16 * HSTRIDE + g * 16 + quad * 4] = pack4(f01, f23);
        }
        half8 f0 = *(const half8*)&h_tile[w][rA * HSTRIDE + fc];
        half8 f1 = *(const half8*)&h_tile[w][(8 + rA) * HSTRIDE + fc];

        // 6. epilogue: packed-f16 interp + filter-mul (2 terms only in f16),
        //    flushed to f32 accumulators every iteration
        const __half2* gj0p = (const __half2*)&gj0;
        const __half2* gk0p = (const __half2*)&gk0;
        const __half2* gj1p = (const __half2*)&gj1;
        const __half2* gk1p = (const __half2*)&gk1;
        const __half2* f0p = (const __half2*)&f0;
        const __half2* f1p = (const __half2*)&f1;
#pragma unroll
        for (int p = 0; p < 4; ++p) {
            __half2 fv0 = __hfma2(wj0, gj0p[p], __hmul2(wk0, gk0p[p]));
            __half2 fv1 = __hfma2(wj1, gj1p[p], __hmul2(wk1, gk1p[p]));
            __half2 tot = __hfma2(f1p[p], fv1, __hmul2(f0p[p], fv0));
            acc[2 * p]     += __low2float(tot);
            acc[2 * p + 1] += __high2float(tot);
        }
    }

    // ---- reduce over row-groups within wave ----
#pragma unroll
    for (int i = 0; i < 8; ++i) {
        acc[i] += __shfl_xor(acc[i], 8, 64);
        acc[i] += __shfl_xor(acc[i], 16, 64);
        acc[i] += __shfl_xor(acc[i], 32, 64);
    }
    if (lane < 8)
#pragma unroll
        for (int i = 0; i < 8; ++i) red[w][lane * 8 + i] = acc[i];
    __syncthreads();

    if (tid < FF)
        partial[(split * (BB * AA) + ba) * FF + tid] =
            red[0][tid] + red[1][tid] + red[2][tid] + red[3][tid];
}

// Kernel 3: sum the NSPLIT partials, f2out matvec + ssp
__global__ void out_kernel(const float* __restrict__ partial,
                           const float* __restrict__ Wf,
                           const float* __restrict__ bf,
                           float* __restrict__ out) {
    __shared__ float yag[FF];
    const int ba = blockIdx.x;
    const int t = threadIdx.x;  // 128
    if (t < FF) {
        float s = 0.f;
#pragma unroll
        for (int sp = 0; sp < NSPLIT; ++sp)
            s += partial[(sp * (BB * AA) + ba) * FF + t];
        yag[t] = s;
    }
    __syncthreads();
    float a = bf[t];
#pragma unroll 8
    for (int f = 0; f < FF; ++f) a += yag[f] * Wf[f * DOUT + t];
    out[(long)ba * DOUT + t] = ssp_f(a);
}

extern "C" void kernel_launch(void* const* d_in, const int* in_sizes, int n_in,
                              void* d_out, int out_size, void* d_ws, size_t ws_size,
                              hipStream_t stream) {
    const float* x       = (const float*)d_in[0];
    const float* r_ij    = (const float*)d_in[2];
    const float* r_ik    = (const float*)d_in[3];
    const int*   nbrj    = (const int*)d_in[7];
    const int*   nbrk    = (const int*)d_in[8];
    const float* tmask   = (const float*)d_in[9];
    const float* d_ijk   = (const float*)d_in[10];
    const float* W_in2f  = (const float*)d_in[11];
    const float* W_t1    = (const float*)d_in[12];
    const float* b_t1    = (const float*)d_in[13];
    const float* W_t2    = (const float*)d_in[14];
    const float* b_t2    = (const float*)d_in[15];
    const float* W_f2out = (const float*)d_in[16];
    const float* b_f2out = (const float*)d_in[17];
    float* out = (float*)d_out;

    char* ws = (char*)d_ws;
    _Float16* y      = (_Float16*)(ws + OFF_Y);
    float* partial   = (float*)(ws + OFF_PARTIAL);
    _Float16* B1tab  = (_Float16*)(ws + OFF_B1);
    _Float16* B2tab  = (_Float16*)(ws + OFF_B2);
    _Float16* BPtab  = (_Float16*)(ws + OFF_BP);

    in2f_prep_kernel<<<BB * AA, 64, 0, stream>>>(x, W_in2f, y, W_t1, b_t1,
                                                 W_t2, b_t2, B1tab, B2tab, BPtab);
    triple_kernel<<<BB * AA * NSPLIT, 256, 0, stream>>>(nbrj, nbrk, r_ij, r_ik,
                                                        tmask, d_ijk, B1tab, B2tab,
                                                        BPtab, y, partial);
    out_kernel<<<BB * AA, 128, 0, stream>>>(partial, W_f2out, b_f2out, out);
}